// Round 7
// baseline (410.587 us; speedup 1.0000x reference)
//
#include <hip/hip_runtime.h>
#include <hip/hip_fp16.h>

// VQ codebook argmin: N=32768 queries x K=8192 codes x D=256 fp32.
// f16 hi/lo split (3 MFMA terms) => fp32-accurate dots on the matrix pipe;
// fused running argmin. Scaling (exact powers of 2, argmin-invariant):
// z*=2^4, e*=2^15; dist_scaled = 2^19*cb_sq - 2*acc.
//
// R8: 4 WAVES/SIMD. R7 (2 waves/SIMD, barrier-free) landed at MfmaUtil
// 63% == MFMA-floor/duration: the remaining 37% is each wave's own
// VALU/load latency with only one sibling wave to hide behind. Per-CU
// work is occupancy-invariant here, so double the siblings: 64-query
// A panels (64KB LDS), grid 512 => 2 blocks/CU = 16 waves/CU = 4/SIMD.
// VGPR 92 <= 128 allows it; launch_bounds stays (512,2) as a floor
// (R3 lesson: forcing occupancy via the bounds arg causes spills).
// Waves split (p: ct-quarter, v: col-half); everything else identical.

#define N_Q   32768
#define K_CB  8192
#define D_DIM 256

typedef _Float16 half8 __attribute__((ext_vector_type(8)));
typedef float    f32x4 __attribute__((ext_vector_type(4)));

__device__ __forceinline__ void gl_lds16(const _Float16* g, _Float16* l) {
  __builtin_amdgcn_global_load_lds(
      (const __attribute__((address_space(1))) unsigned int*)g,
      (__attribute__((address_space(3))) unsigned int*)l, 16, 0, 0);
}

// Frag-major layouts (half8 index):
//   zpk: ((qb*64 + q16*8 + kk)*2 + hl)*64 + l
//        = z[qb*128 + q16*16 + (l&15)][kk*32 + (l>>4)*8 + j]  (*2^4, hi/lo)
//   epk: ((c16*8  + kk)*2 + hl)*64 + l
//        = e[c16*16 + (l&15)][kk*32 + (l>>4)*8 + j]           (*2^15, hi/lo)
// Matches mfma_f32_16x16x32_f16 A/B layout: row/col = lane&15,
// k = (lane>>4)*8 + j. A 64-query half of a qb is a contiguous 64KB run.

__global__ void vq_prep_z(const float* __restrict__ z, _Float16* __restrict__ zpk) {
  int t = blockIdx.x * 256 + threadIdx.x;    // 1,048,576 threads
  int l = t & 63, g = t >> 6;                // g = qb*64 + q16*8 + kk
  int qb = g >> 6, q16 = (g >> 3) & 7, kk = g & 7;
  int row = qb * 128 + q16 * 16 + (l & 15);
  int kc  = kk * 32 + (l >> 4) * 8;
  const float4* zp = (const float4*)(z + (size_t)row * 256 + kc);
  float4 a = zp[0], b = zp[1];
  float xs[8] = {a.x, a.y, a.z, a.w, b.x, b.y, b.z, b.w};
  half8 hh, ll;
#pragma unroll
  for (int j = 0; j < 8; ++j) {
    float x = xs[j] * 16.0f;
    _Float16 hj = (_Float16)x;
    hh[j] = hj; ll[j] = (_Float16)(x - (float)hj);
  }
  ((half8*)zpk)[(size_t)g * 128 + l]      = hh;
  ((half8*)zpk)[(size_t)g * 128 + 64 + l] = ll;
}

__global__ void vq_prep_e(const float* __restrict__ cb, _Float16* __restrict__ epk) {
  int t = blockIdx.x * 256 + threadIdx.x;    // 262,144 threads
  int l = t & 63, g = t >> 6;                // g = c16*8 + kk
  int c16 = g >> 3, kk = g & 7;
  int code = c16 * 16 + (l & 15);
  int kc   = kk * 32 + (l >> 4) * 8;
  const float4* ep = (const float4*)(cb + (size_t)code * 256 + kc);
  float4 a = ep[0], b = ep[1];
  float xs[8] = {a.x, a.y, a.z, a.w, b.x, b.y, b.z, b.w};
  half8 hh, ll;
#pragma unroll
  for (int j = 0; j < 8; ++j) {
    float x = xs[j] * 32768.0f;
    _Float16 hj = (_Float16)x;
    hh[j] = hj; ll[j] = (_Float16)(x - (float)hj);
  }
  ((half8*)epk)[(size_t)g * 128 + l]      = hh;
  ((half8*)epk)[(size_t)g * 128 + 64 + l] = ll;
}

// cbs[code] = 2^19 * ||e_code||^2  (unscaled sum, like reference)
__global__ void vq_prep_cbs(const float* __restrict__ cb, float* __restrict__ cbs) {
  int w = threadIdx.x >> 6, lane = threadIdx.x & 63;
  int code = blockIdx.x * 4 + w;             // wave per code
  float4 v = ((const float4*)cb)[code * 64 + lane];
  float ss = v.x * v.x + v.y * v.y + v.z * v.z + v.w * v.w;
#pragma unroll
  for (int off = 1; off < 64; off <<= 1) ss += __shfl_xor(ss, off);
  if (lane == 0) cbs[code] = ss * 524288.0f;
}

// ---------------- main: fused GEMM + running argmin ----------------
// Grid 512 blocks (2/CU: LDS 64KB). Block = 512 thr = 8 waves; with
// VGPR<=128 that's 16 waves/CU = 4/SIMD. Wave (p,v): all 64 block rows,
// cols v*64..+64 of ct = p*16+i, i in 0..16. No barriers in main loop.
__global__ __launch_bounds__(512, 2)
void vq_main(const _Float16* __restrict__ zpk, const _Float16* __restrict__ epk,
             const float* __restrict__ cbs, int* __restrict__ out) {
  __shared__ __align__(16) char smem[65536];    // A panel (64 q), frag-major
  _Float16* const A = (_Float16*)smem;

  const int tid  = threadIdx.x;
  const int lane = tid & 63;
  const int w    = tid >> 6;       // 0..7
  const int v    = w & 1;          // code-col half within ct
  const int p    = w >> 1;         // ct quarter (16 cts each)
  const int q    = lane & 15;
  const int quad = lane >> 4;
  const int b    = blockIdx.x;     // 64-query tile id
  const int q0   = b * 64;

  // Prologue: linear 64KB copy of this block's frag-major A panel.
  {
    const _Float16* src = zpk + (size_t)b * 32768;
    for (int c = 0; c < 8; ++c) {
      const int off = (c * 512 + tid) * 8;     // f16 elems (16B/thread)
      gl_lds16(src + off, A + off);
    }
  }
  __syncthreads();   // drains vmcnt; A read-only from here on

  // A frags (LDS, half8 units): Ab[mt*1024 + kk*128 (+64 for lo)]
  const half8* const Ab = (const half8*)A + lane;
  // B frags (global, half8 units): ebi[nt*1024 + kk*128 (+64 for lo)]
  const half8* const eb = (const half8*)epk + (size_t)v * 4096 + lane;

  float    rd[16];
  unsigned rc[16];
#pragma unroll
  for (int i = 0; i < 16; ++i) { rd[i] = 3.0e38f; rc[i] = 0u; }

  for (int i = 0; i < 16; ++i) {
    const int ct   = p * 16 + i;
    const int col0 = ct * 128 + v * 64 + q;
    const half8* const ebi = eb + (size_t)ct * 8192;

    float cbsv[4];
#pragma unroll
    for (int nt = 0; nt < 4; ++nt) cbsv[nt] = cbs[col0 + nt * 16];

    f32x4 acc[4][4];
#pragma unroll
    for (int mt = 0; mt < 4; ++mt)
#pragma unroll
      for (int nt = 0; nt < 4; ++nt)
        acc[mt][nt] = (f32x4){0.f, 0.f, 0.f, 0.f};

#pragma unroll 2
    for (int kk = 0; kk < 8; ++kk) {
      half8 bh[4], bl[4], ah[4], al[4];
#pragma unroll
      for (int nt = 0; nt < 4; ++nt) {
        bh[nt] = ebi[nt * 1024 + kk * 128];
        bl[nt] = ebi[nt * 1024 + kk * 128 + 64];
      }
#pragma unroll
      for (int mt = 0; mt < 4; ++mt) {
        ah[mt] = Ab[mt * 1024 + kk * 128];
        al[mt] = Ab[mt * 1024 + kk * 128 + 64];
      }
#pragma unroll
      for (int mt = 0; mt < 4; ++mt)
#pragma unroll
        for (int nt = 0; nt < 4; ++nt) {
          acc[mt][nt] = __builtin_amdgcn_mfma_f32_16x16x32_f16(ah[mt], bh[nt], acc[mt][nt], 0, 0, 0);
          acc[mt][nt] = __builtin_amdgcn_mfma_f32_16x16x32_f16(ah[mt], bl[nt], acc[mt][nt], 0, 0, 0);
          acc[mt][nt] = __builtin_amdgcn_mfma_f32_16x16x32_f16(al[mt], bh[nt], acc[mt][nt], 0, 0, 0);
        }
    }

    // dist = 2^19*cb_sq - 2*acc; running (min,idx). Ascending nt / i =>
    // strict < keeps the lowest index on ties.
#pragma unroll
    for (int mt = 0; mt < 4; ++mt)
#pragma unroll
      for (int r = 0; r < 4; ++r) {
        float d = fmaf(-2.0f, acc[mt][0][r], cbsv[0]);
        unsigned cidx = (unsigned)col0;
#pragma unroll
        for (int nt = 1; nt < 4; ++nt) {
          float dn = fmaf(-2.0f, acc[mt][nt][r], cbsv[nt]);
          if (dn < d) { d = dn; cidx = (unsigned)(col0 + nt * 16); }
        }
        int ri = mt * 4 + r;
        if (d < rd[ri]) { rd[ri] = d; rc[ri] = cidx; }
      }
  }

  // Reduce: 16-lane groups hold 16 cols of the same rows; then combine the
  // 8 (p,v) candidates per row via LDS (overlaying dead A region).
  // w ascending == (p,v) lex == ascending col ranges -> strict < keeps
  // the lowest index on ties.
  __syncthreads();                       // all waves done reading A
  float*    const redD = (float*)smem;   // [8][64]
  unsigned* const redC = (unsigned*)(smem + 2048);

#pragma unroll
  for (int ri = 0; ri < 16; ++ri) {
    float d = rd[ri]; unsigned cidx = rc[ri];
#pragma unroll
    for (int off = 1; off < 16; off <<= 1) {
      float od = __shfl_xor(d, off);
      unsigned oc = __shfl_xor(cidx, off);
      if (od < d || (od == d && oc < cidx)) { d = od; cidx = oc; }
    }
    if (q == 0) {
      int row = (ri >> 2) * 16 + quad * 4 + (ri & 3);   // 0..63
      redD[w * 64 + row] = d;
      redC[w * 64 + row] = cidx;
    }
  }
  __syncthreads();
  if (tid < 64) {
    float d0 = redD[tid]; unsigned c0 = redC[tid];
#pragma unroll
    for (int s = 1; s < 8; ++s) {
      float ds = redD[s * 64 + tid]; unsigned cs = redC[s * 64 + tid];
      if (ds < d0 || (ds == d0 && cs < c0)) { d0 = ds; c0 = cs; }
    }
    out[q0 + tid] = (int)c0;
  }
}

extern "C" void kernel_launch(void* const* d_in, const int* in_sizes, int n_in,
                              void* d_out, int out_size, void* d_ws, size_t ws_size,
                              hipStream_t stream) {
  const float* z  = (const float*)d_in[0];   // [32,32,32,256] fp32
  const float* cb = (const float*)d_in[1];   // [8192,256] fp32
  char* ws = (char*)d_ws;
  // ws layout (~40 MB): zpk 32M (frag-major z hi/lo) | epk 8M | cbs 32K
  _Float16* zpk = (_Float16*)(ws);
  _Float16* epk = (_Float16*)(ws + (size_t)32 * 1024 * 1024);
  float*    cbs = (float*)(ws + (size_t)40 * 1024 * 1024);

  hipLaunchKernelGGL(vq_prep_z,   dim3(4096), dim3(256), 0, stream, z, zpk);
  hipLaunchKernelGGL(vq_prep_e,   dim3(1024), dim3(256), 0, stream, cb, epk);
  hipLaunchKernelGGL(vq_prep_cbs, dim3(2048), dim3(256), 0, stream, cb, cbs);
  hipLaunchKernelGGL(vq_main,     dim3(512),  dim3(512), 0, stream,
                     zpk, epk, cbs, (int*)d_out);
}